// Round 8
// baseline (46.553 us; speedup 1.0000x reference)
//
#include <hip/hip_runtime.h>

// OurButterflyLayer: N=4096, LOGN=12, IN=1024, OUT=4096, BATCH=8192
//
// out[s,j] = scale[j] * z_s[src[j]],  z_s = 10-stage butterfly (stages 0..9)
// on the 1024-float input row s; stages 10,11 + out-row gather fold into
// per-output (scale, src) pairs (elements >=1024 stay zero through stages
// 0..9 since all strides < 1024).
//
// Round-8: R7 store path (plain stores, pipelined epilogue loads) + 4
// samples/wave amortization. 512 blocks x 256 thr, 4 waves, 4 samples/wave.
// 64 KB LDS union: stage-5..9 coeffs (40 KB, swizzled) reused after barrier
// as per-wave float4 z-slots -> ONE ds_read_b128 + one src/scale read pair
// serves FOUR samples in the epilogue. Exchanges: verified DPP d=1,2,8 +
// shfl d=4,16,32.

typedef float f4 __attribute__((ext_vector_type(4)));
typedef int   i4 __attribute__((ext_vector_type(4)));

__device__ __forceinline__ int swz(int e) {
    // XOR float-index bits [6:5] into [3:2]: keeps float4 alignment; makes
    // 64B-stride LDS coeff accesses bank-conflict-free.
    return e ^ (((e >> 5) & 3) << 2);
}

template<int CTRL>
__device__ __forceinline__ float dppx(float x) {
    int xi = __builtin_bit_cast(int, x);
    int r  = __builtin_amdgcn_update_dpp(xi, xi, CTRL, 0xF, 0xF, true);
    return __builtin_bit_cast(float, r);
}
// ctrl: quad_perm(1,0,3,2)=0xB1 (lane^1), quad_perm(2,3,0,1)=0x4E (lane^2),
// row_ror:8=0x128 (lane^8 within 16-lane row). All verified in R4/R6/R7.

__global__ void __launch_bounds__(256) bfly_prep(
    const float* __restrict__ lp, const int* __restrict__ orow,
    float* __restrict__ scale, int* __restrict__ src4)
{
    int j = blockIdx.x * 256 + threadIdx.x;
    if (j >= 4096) return;
    int r = orow[j];
    int c = r & 1023;
    int u = r & 2047;
    const float* A10 = lp + 20 * 4096;
    const float* B10 = lp + 21 * 4096;
    const float* A11 = lp + 22 * 4096;
    const float* B11 = lp + 23 * 4096;
    float f11 = (r & 2048) ? B11[u] : A11[u];
    float f10 = (r & 1024) ? B10[c] : A10[c];
    scale[j] = f11 * f10;
    // float4-slot index with bank-spreading bijection (XOR bits[6:4] into
    // bits[2:0]); matches the write-side (lane*16+k)^(lane&7) since k<16.
    src4[j] = c ^ ((c >> 4) & 7);
}

__global__ void __launch_bounds__(256, 2) bfly_main(
    const float* __restrict__ inp, const float* __restrict__ lp,
    const float* __restrict__ scale, const int* __restrict__ src4,
    float* __restrict__ out)
{
    // union: [0..10240) = stage-5..9 coeffs (swizzled) until 2nd barrier;
    // afterwards the full 16384 floats are 4 x 1024 float4 z-slots.
    __shared__ __align__(16) float smem[16384];
    const int t = threadIdx.x;
    const int wave = t >> 6, lane = t & 63;

    // cooperative coeff staging: lp rows 10..19, first 1024 floats of each
    #pragma unroll
    for (int q = 0; q < 10; ++q) {
        const f4 v = *reinterpret_cast<const f4*>(lp + (size_t)(10 + q) * 4096 + t * 4);
        *reinterpret_cast<f4*>(&smem[q * 1024 + swz(t * 4)]) = v;
    }

    const int sBase = blockIdx.x * 16 + wave * 4;   // 4 samples per wave
    float x[4][16];
    #pragma unroll
    for (int m = 0; m < 4; ++m) {
        const f4* p = reinterpret_cast<const f4*>(inp + (size_t)(sBase + m) * 1024 + lane * 16);
        #pragma unroll
        for (int c = 0; c < 4; ++c) {
            f4 v = p[c];
            x[m][4*c+0] = v.x; x[m][4*c+1] = v.y; x[m][4*c+2] = v.z; x[m][4*c+3] = v.w;
        }
    }

    __syncthreads();   // coeffs ready

    // stages 0..3: coeff from global (L1-hot), pairs inside the lane's 16 regs
    #pragma unroll
    for (int i = 0; i < 4; ++i) {
        float a[16], b[16];
        const f4* A = reinterpret_cast<const f4*>(lp + (size_t)(2*i)   * 4096 + lane * 16);
        const f4* B = reinterpret_cast<const f4*>(lp + (size_t)(2*i+1) * 4096 + lane * 16);
        #pragma unroll
        for (int c = 0; c < 4; ++c) {
            f4 va = A[c], vb = B[c];
            a[4*c+0]=va.x; a[4*c+1]=va.y; a[4*c+2]=va.z; a[4*c+3]=va.w;
            b[4*c+0]=vb.x; b[4*c+1]=vb.y; b[4*c+2]=vb.z; b[4*c+3]=vb.w;
        }
        const int s = 1 << i;
        #pragma unroll
        for (int m = 0; m < 4; ++m) {
            #pragma unroll
            for (int k = 0; k < 16; ++k) {
                if (!(k & s)) {
                    float lo = x[m][k], hi = x[m][k | s];
                    x[m][k]     = a[k]     * lo + b[k | s] * hi;
                    x[m][k | s] = a[k | s] * hi + b[k]     * lo;
                }
            }
        }
    }

    // stage 4 (d=1): coeff from global rows 8,9; exchange via DPP quad_perm
    {
        float a[16], b[16];
        const f4* A = reinterpret_cast<const f4*>(lp + (size_t)8 * 4096 + lane * 16);
        const f4* B = reinterpret_cast<const f4*>(lp + (size_t)9 * 4096 + (lane ^ 1) * 16);
        #pragma unroll
        for (int c = 0; c < 4; ++c) {
            f4 va = A[c], vb = B[c];
            a[4*c+0]=va.x; a[4*c+1]=va.y; a[4*c+2]=va.z; a[4*c+3]=va.w;
            b[4*c+0]=vb.x; b[4*c+1]=vb.y; b[4*c+2]=vb.z; b[4*c+3]=vb.w;
        }
        #pragma unroll
        for (int m = 0; m < 4; ++m)
            #pragma unroll
            for (int k = 0; k < 16; ++k) {
                float v = x[m][k];
                x[m][k] = a[k] * v + b[k] * dppx<0xB1>(v);
            }
    }

    // stages 5..9: coeff from swizzled LDS; exchange via verified DPP/shfl
    #pragma unroll
    for (int i = 5; i < 10; ++i) {
        const int d = 1 << (i - 4);
        float a[16], b[16];
        const float* arow = &smem[(size_t)(i - 5) * 2048];
        const float* brow = arow + 1024;
        #pragma unroll
        for (int c = 0; c < 4; ++c) {
            f4 va = *reinterpret_cast<const f4*>(&arow[swz(lane * 16 + 4 * c)]);
            f4 vb = *reinterpret_cast<const f4*>(&brow[swz((lane ^ d) * 16 + 4 * c)]);
            a[4*c+0]=va.x; a[4*c+1]=va.y; a[4*c+2]=va.z; a[4*c+3]=va.w;
            b[4*c+0]=vb.x; b[4*c+1]=vb.y; b[4*c+2]=vb.z; b[4*c+3]=vb.w;
        }
        #pragma unroll
        for (int m = 0; m < 4; ++m) {
            #pragma unroll
            for (int k = 0; k < 16; ++k) {
                float v = x[m][k];
                float xp = (d == 2) ? dppx<0x4E>(v)
                         : (d == 8) ? dppx<0x128>(v)
                         :            __shfl_xor(v, d, 64);   // d = 4, 16, 32
                x[m][k] = a[k] * v + b[k] * xp;
            }
        }
    }

    __syncthreads();   // all coeff reads done; reuse smem as float4 z-slots

    f4* zz = reinterpret_cast<f4*>(smem) + (size_t)wave * 1024;

    // z write: slot (lane*16+k)^(lane&7) holds {z0,z1,z2,z3}[c]
    const int km = lane & 7;
    #pragma unroll
    for (int k = 0; k < 16; ++k) {
        f4 v = { x[0][k], x[1][k], x[2][k], x[3][k] };
        zz[(lane * 16 + k) ^ km] = v;
    }

    // epilogue: one b128 LDS read + one src/scale pair serves 4 samples;
    // loads pipelined 1 deep ahead of the stores.
    const i4* srv = reinterpret_cast<const i4*>(src4);
    const f4* scv = reinterpret_cast<const f4*>(scale);
    f4* o0 = reinterpret_cast<f4*>(out + (size_t)(sBase + 0) * 4096);
    f4* o1 = reinterpret_cast<f4*>(out + (size_t)(sBase + 1) * 4096);
    f4* o2 = reinterpret_cast<f4*>(out + (size_t)(sBase + 2) * 4096);
    f4* o3 = reinterpret_cast<f4*>(out + (size_t)(sBase + 3) * 4096);

    i4 si = srv[lane];
    f4 sc = scv[lane];
    #pragma unroll
    for (int it = 0; it < 16; ++it) {
        i4 si_c = si;
        f4 sc_c = sc;
        if (it + 1 < 16) {                      // prefetch next iteration
            si = srv[(it + 1) * 64 + lane];
            sc = scv[(it + 1) * 64 + lane];
        }
        int j4 = it * 64 + lane;
        f4 vx = zz[si_c.x];
        f4 vy = zz[si_c.y];
        f4 vz = zz[si_c.z];
        f4 vw = zz[si_c.w];
        f4 r0 = { sc_c.x * vx[0], sc_c.y * vy[0], sc_c.z * vz[0], sc_c.w * vw[0] };
        f4 r1 = { sc_c.x * vx[1], sc_c.y * vy[1], sc_c.z * vz[1], sc_c.w * vw[1] };
        f4 r2 = { sc_c.x * vx[2], sc_c.y * vy[2], sc_c.z * vz[2], sc_c.w * vw[2] };
        f4 r3 = { sc_c.x * vx[3], sc_c.y * vy[3], sc_c.z * vz[3], sc_c.w * vw[3] };
        o0[j4] = r0;
        o1[j4] = r1;
        o2[j4] = r2;
        o3[j4] = r3;
    }
}

extern "C" void kernel_launch(void* const* d_in, const int* in_sizes, int n_in,
                              void* d_out, int out_size, void* d_ws, size_t ws_size,
                              hipStream_t stream) {
    const float* inp  = (const float*)d_in[0];   // (8192, 1024) f32
    const float* lp   = (const float*)d_in[1];   // (24, 4096)  f32
    const int*   orow = (const int*)d_in[2];     // (4096,)     i32
    float* out = (float*)d_out;                  // (8192, 4096) f32

    float* scale = (float*)d_ws;                       // 4096 f32
    int*   src4  = (int*)((char*)d_ws + 4096 * 4);     // 4096 i32 (f4-slot idx)

    bfly_prep<<<16, 256, 0, stream>>>(lp, orow, scale, src4);
    bfly_main<<<512, 256, 0, stream>>>(inp, lp, scale, src4, out);
}